// Round 1
// baseline (1650.830 us; speedup 1.0000x reference)
//
#include <hip/hip_runtime.h>

typedef unsigned short u16;
typedef __attribute__((ext_vector_type(8))) __bf16 bf16x8;
typedef __attribute__((ext_vector_type(16))) float f32x16;

#define F32(x) ((float)(x))

// dopri5 tableau (double rationals cast to float)
constexpr float DA10 = F32(1.0/5.0);
constexpr float DA20 = F32(3.0/40.0),      DA21 = F32(9.0/40.0);
constexpr float DA30 = F32(44.0/45.0),     DA31 = F32(-56.0/15.0),    DA32 = F32(32.0/9.0);
constexpr float DA40 = F32(19372.0/6561.0),DA41 = F32(-25360.0/2187.0),DA42 = F32(64448.0/6561.0), DA43 = F32(-212.0/729.0);
constexpr float DA50 = F32(9017.0/3168.0), DA51 = F32(-355.0/33.0),   DA52 = F32(46732.0/5247.0), DA53 = F32(49.0/176.0), DA54 = F32(-5103.0/18656.0);
constexpr float DB50 = F32(35.0/384.0), DB52 = F32(500.0/1113.0), DB53 = F32(125.0/192.0),
                DB54 = F32(-2187.0/6784.0), DB55 = F32(11.0/84.0);
constexpr float DE0 = F32(35.0/384.0 - 5179.0/57600.0);
constexpr float DE2 = F32(500.0/1113.0 - 7571.0/16695.0);
constexpr float DE3 = F32(125.0/192.0 - 393.0/640.0);
constexpr float DE4 = F32(-2187.0/6784.0 + 92097.0/339200.0);
constexpr float DE5 = F32(11.0/84.0 - 187.0/2100.0);
constexpr float DE6 = F32(-1.0/40.0);

// ws layout (bytes)
#define OFF_WF1   33554432
#define OFF_WF2   33595392
#define OFF_WH1   33636352
#define OFF_WH2   33656832
#define OFF_B1    33665024
#define OFF_B2    33666048
#define OFF_BH1   33666304
#define OFF_BH2   33666816
#define OFF_SC    33666944
#define OFF_PARTS 33667008

__device__ __forceinline__ u16 f2b(float f) {
  union { float f; unsigned u; } v; v.f = f;
  unsigned u = v.u;
  unsigned r = (u + 0x7fffu + ((u >> 16) & 1u)) >> 16;
  return (u16)r;
}
__device__ __forceinline__ float tanh_fast(float x) {
  float e = __expf(2.0f * x);
  return 1.0f - 2.0f / (e + 1.0f);
}
// swizzled LDS index: row stride 384 elems (48 16B-granules), granule ^= row&7
__device__ __forceinline__ int x2i(int r, int c) {
  return r * 384 + ((((c) >> 3) ^ (r & 7)) << 3) + (c & 7);
}

// ---------------- setup: pack weight fragments (bf16, B-operand layout) ----------------
// B-frag for v_mfma_f32_32x32x16_bf16: lane l holds B[k=(l>>5)*8+e][n=l&31], e=0..7 contiguous.
__global__ void setup_kernel(const float* __restrict__ L,
  const float* __restrict__ aw1, const float* __restrict__ ab1,
  const float* __restrict__ aw2, const float* __restrict__ ab2,
  const float* __restrict__ rw1, const float* __restrict__ rb1,
  const float* __restrict__ rw2, const float* __restrict__ rb2,
  const float* __restrict__ ow1, const float* __restrict__ ob1,
  const float* __restrict__ ow2, const float* __restrict__ ob2,
  u16* __restrict__ Wf1, u16* __restrict__ Wf2,
  u16* __restrict__ Wh1, u16* __restrict__ Wh2,
  float* __restrict__ b1c, float* __restrict__ b2c,
  float* __restrict__ bh1, float* __restrict__ bh2)
{
  int gid = blockIdx.x * blockDim.x + threadIdx.x;
  int gstr = gridDim.x * blockDim.x;
  for (int i = gid; i < 20480 + 20480 + 10240 + 4096; i += gstr) {
    float v; u16* dst;
    if (i < 20480) {                    // GEMM1: [K=80][N=256] = [zu] -> [Ha|Hr]
      int j = i;
      int e = j & 7, l = (j >> 3) & 63, t = j >> 9;
      int kc = t % 5, nt = t / 5;
      int k = kc * 16 + (l >> 5) * 8 + e;
      int n = nt * 32 + (l & 31);
      v = (n < 128) ? aw1[n * 80 + k] : rw1[(n - 128) * 80 + k];
      dst = Wf1 + j;
    } else if (i < 40960) {             // GEMM2: [K=320][N=64] = [z|Ha|Hr] -> dz
      int j = i - 20480;
      int e = j & 7, l = (j >> 3) & 63, t = j >> 9;
      int kc = t % 20, nt = t / 20;
      int kk = kc * 16 + (l >> 5) * 8 + e;
      int n = nt * 32 + (l & 31);
      if (kk < 64) {                    // A^T part: W2[k][n] = A[n][k] = -(L L^T)[n][k]
        float s = 0.f;
        for (int q = 0; q < 64; ++q) s += L[n * 64 + q] * L[kk * 64 + q];
        v = -s;
      } else if (kk < 192) v = aw2[n * 128 + (kk - 64)];
      else                 v = rw2[n * 128 + (kk - 192)];
      dst = Wf2 + j;
    } else if (i < 51200) {             // head L1: [K=80][N=128]
      int j = i - 40960;
      int e = j & 7, l = (j >> 3) & 63, t = j >> 9;
      int kc = t % 5, nt = t / 5;
      int k = kc * 16 + (l >> 5) * 8 + e;
      int n = nt * 32 + (l & 31);
      v = ow1[n * 80 + k];
      dst = Wh1 + j;
    } else {                            // head L2: [K=128][N=32 pad of 20]
      int j = i - 51200;
      int e = j & 7, l = (j >> 3) & 63, kc = j >> 9;
      int kk = kc * 16 + (l >> 5) * 8 + e;
      int n = l & 31;
      v = (n < 20) ? ow2[n * 128 + kk] : 0.f;
      dst = Wh2 + j;
    }
    *dst = f2b(v);
  }
  if (gid < 256) b1c[gid] = (gid < 128) ? ab1[gid] : rb1[gid - 128];
  if (gid < 64)  b2c[gid] = ab2[gid] + rb2[gid];
  if (gid < 128) bh1[gid] = ob1[gid];
  if (gid < 32)  bh2[gid] = (gid < 20) ? ob2[gid] : 0.f;
}

// ---------------- init: z state copy + control scalars ----------------
__global__ void init_kernel(const float* __restrict__ zt, float* __restrict__ buf0,
                            float* __restrict__ sc, float* __restrict__ parts)
{
  int gid = blockIdx.x * 256 + threadIdx.x;
  const float4* s = (const float4*)zt;
  float4* d = (float4*)buf0;
  #pragma unroll
  for (int p = 0; p < 4; ++p) { int i = p * 524288 + gid; d[i] = s[i]; }
  if (blockIdx.x == 0) {
    for (int i = threadIdx.x; i < 2048; i += 256) parts[i] = 0.f;
    if (threadIdx.x == 0) {
      sc[0] = 0.f;            // t
      sc[1] = 0.1f;           // h
      ((int*)sc)[2] = 0;      // done
      ((int*)sc)[3] = 0;      // (unused)
      ((int*)sc)[4] = 0;      // cur (z-buffer parity)
    }
  }
}

// ---------------- one dopri5 step for a 64-row tile ----------------
__global__ __launch_bounds__(256, 1) void step_kernel(
  const float* __restrict__ ut,
  const u16* __restrict__ Wf1, const u16* __restrict__ Wf2,
  const float* __restrict__ b1c, const float* __restrict__ b2c,
  const float* __restrict__ sc, float* __restrict__ parts,
  float* __restrict__ buf0, float* __restrict__ buf1)
{
  if (((const int*)sc)[2]) return;   // done
  __shared__ __align__(16) u16 X2[64 * 384];   // [z(64)|u(16)|H(256)] bf16, swizzled
  __shared__ float b1s[256];
  __shared__ float b2s[64];
  __shared__ float wpart[4];
  const int tid = threadIdx.x;
  const float t = sc[0], h = sc[1];
  const int cur = ((const int*)sc)[4];
  const float h_eff = fminf(h, 1.0f - t);
  const float* __restrict__ zin  = cur ? buf1 : buf0;
  float* __restrict__       yout = cur ? buf0 : buf1;
  const int w = tid >> 6, l = tid & 63, lo = l & 31, hi = l >> 5;
  const int R0 = blockIdx.x * 64;
  if (tid < 256) b1s[tid] = b1c[tid];
  if (tid < 64)  b2s[tid] = b2c[tid];
  // wave roles
  const int mt1 = w & 1, ntg = (w >> 1) * 4;   // GEMM1: Mtile, Ntile group (4)
  const int mt2 = w >> 1, nt2 = w & 1;         // GEMM2: Mtile, Ntile

  // weight fragments in registers
  bf16x8 wf1[4][5];
  #pragma unroll
  for (int nt = 0; nt < 4; ++nt)
    #pragma unroll
    for (int kc = 0; kc < 5; ++kc)
      wf1[nt][kc] = *(const bf16x8*)(Wf1 + (((ntg + nt) * 5 + kc) * 64 + l) * 8);
  bf16x8 wf2[20];
  #pragma unroll
  for (int kc = 0; kc < 20; ++kc)
    wf2[kc] = *(const bf16x8*)(Wf2 + ((nt2 * 20 + kc) * 64 + l) * 8);

  const int c2 = nt2 * 32 + lo;                // owned output latent col
  const float b2v = b2c[c2];

  // z state for owned positions (C-layout of 32x32: row=(j&3)+8*(j>>2)+4*hi)
  f32x16 z;
  #pragma unroll
  for (int j = 0; j < 16; ++j) {
    int rr = mt2 * 32 + (j & 3) + 8 * (j >> 2) + 4 * hi;
    z[j] = zin[(size_t)(R0 + rr) * 64 + c2];
  }
  // u section (static over the step)
  for (int idx = tid; idx < 1024; idx += 256) {
    int r = idx >> 4, uc = idx & 15;
    X2[x2i(r, 64 + uc)] = f2b(ut[(size_t)(R0 + r) * 16 + uc]);
  }
  // stage-1 input = z
  #pragma unroll
  for (int j = 0; j < 16; ++j) {
    int rr = mt2 * 32 + (j & 3) + 8 * (j >> 2) + 4 * hi;
    X2[x2i(rr, c2)] = f2b(z[j]);
  }

  auto feval = [&](f32x16& kout) {
    __syncthreads();                           // zi (and H-region reuse) visible
    // GEMM1: [64,80] @ [80,256]
    f32x16 a1[4];
    #pragma unroll
    for (int nt = 0; nt < 4; ++nt)
      #pragma unroll
      for (int j = 0; j < 16; ++j) a1[nt][j] = 0.f;
    const int ar1 = mt1 * 32 + lo;
    #pragma unroll
    for (int kc = 0; kc < 5; ++kc) {
      const bf16x8 af = *(const bf16x8*)&X2[ar1 * 384 + (((kc * 2 + hi) ^ (ar1 & 7)) << 3)];
      #pragma unroll
      for (int nt = 0; nt < 4; ++nt)
        a1[nt] = __builtin_amdgcn_mfma_f32_32x32x16_bf16(af, wf1[nt][kc], a1[nt], 0, 0, 0);
    }
    // tanh + write H section
    #pragma unroll
    for (int nt = 0; nt < 4; ++nt) {
      const int n = (ntg + nt) * 32 + lo;
      const float bb = b1s[n];
      #pragma unroll
      for (int j = 0; j < 16; ++j) {
        float th = tanh_fast(a1[nt][j] + bb);
        int rr = mt1 * 32 + (j & 3) + 8 * (j >> 2) + 4 * hi;
        X2[x2i(rr, 80 + n)] = f2b(th);
      }
    }
    __syncthreads();                           // all H written
    // GEMM2: [64, 320] @ [320,64]   (K = z(64) + H(256), skipping u cols)
    f32x16 a2;
    #pragma unroll
    for (int j = 0; j < 16; ++j) a2[j] = 0.f;
    const int ar2 = mt2 * 32 + lo;
    #pragma unroll
    for (int kc = 0; kc < 20; ++kc) {
      const int col0 = (kc < 4 ? kc * 16 : kc * 16 + 16) + hi * 8;
      const bf16x8 af = *(const bf16x8*)&X2[ar2 * 384 + (((col0 >> 3) ^ (ar2 & 7)) << 3)];
      a2 = __builtin_amdgcn_mfma_f32_32x32x16_bf16(af, wf2[kc], a2, 0, 0, 0);
    }
    __syncthreads();                           // reads done before next zi overwrite
    #pragma unroll
    for (int j = 0; j < 16; ++j) kout[j] = a2[j] + b2v;
  };

  f32x16 ks0, ks1, ks2, ks3, kp, yac, eac;
  // stage 1
  feval(kp);
  #pragma unroll
  for (int j = 0; j < 16; ++j) { ks0[j] = kp[j]; yac[j] = DB50 * kp[j]; eac[j] = DE0 * kp[j]; }
  // stage 2
  #pragma unroll
  for (int j = 0; j < 16; ++j) {
    int rr = mt2 * 32 + (j & 3) + 8 * (j >> 2) + 4 * hi;
    X2[x2i(rr, c2)] = f2b(z[j] + h_eff * (DA10 * ks0[j]));
  }
  feval(kp);
  #pragma unroll
  for (int j = 0; j < 16; ++j) ks1[j] = kp[j];   // B5[1]=E[1]=0
  // stage 3
  #pragma unroll
  for (int j = 0; j < 16; ++j) {
    int rr = mt2 * 32 + (j & 3) + 8 * (j >> 2) + 4 * hi;
    X2[x2i(rr, c2)] = f2b(z[j] + h_eff * (DA20 * ks0[j] + DA21 * ks1[j]));
  }
  feval(kp);
  #pragma unroll
  for (int j = 0; j < 16; ++j) { ks2[j] = kp[j]; yac[j] += DB52 * kp[j]; eac[j] += DE2 * kp[j]; }
  // stage 4
  #pragma unroll
  for (int j = 0; j < 16; ++j) {
    int rr = mt2 * 32 + (j & 3) + 8 * (j >> 2) + 4 * hi;
    X2[x2i(rr, c2)] = f2b(z[j] + h_eff * (DA30 * ks0[j] + DA31 * ks1[j] + DA32 * ks2[j]));
  }
  feval(kp);
  #pragma unroll
  for (int j = 0; j < 16; ++j) { ks3[j] = kp[j]; yac[j] += DB53 * kp[j]; eac[j] += DE3 * kp[j]; }
  // stage 5
  #pragma unroll
  for (int j = 0; j < 16; ++j) {
    int rr = mt2 * 32 + (j & 3) + 8 * (j >> 2) + 4 * hi;
    X2[x2i(rr, c2)] = f2b(z[j] + h_eff * (DA40 * ks0[j] + DA41 * ks1[j] + DA42 * ks2[j] + DA43 * ks3[j]));
  }
  feval(kp);                                    // kp = k5
  #pragma unroll
  for (int j = 0; j < 16; ++j) { yac[j] += DB54 * kp[j]; eac[j] += DE4 * kp[j]; }
  // stage 6 (uses k5 = kp before overwrite)
  #pragma unroll
  for (int j = 0; j < 16; ++j) {
    int rr = mt2 * 32 + (j & 3) + 8 * (j >> 2) + 4 * hi;
    X2[x2i(rr, c2)] = f2b(z[j] + h_eff * (DA50 * ks0[j] + DA51 * ks1[j] + DA52 * ks2[j] + DA53 * ks3[j] + DA54 * kp[j]));
  }
  feval(kp);                                    // kp = k6
  #pragma unroll
  for (int j = 0; j < 16; ++j) { yac[j] += DB55 * kp[j]; eac[j] += DE5 * kp[j]; }
  // stage 7 input = y_new = z + h*sum(B5 k)
  #pragma unroll
  for (int j = 0; j < 16; ++j) {
    int rr = mt2 * 32 + (j & 3) + 8 * (j >> 2) + 4 * hi;
    X2[x2i(rr, c2)] = f2b(z[j] + h_eff * yac[j]);
  }
  feval(kp);                                    // kp = k7
  #pragma unroll
  for (int j = 0; j < 16; ++j) eac[j] += DE6 * kp[j];

  // finalize: y write + error partial
  float p = 0.f;
  #pragma unroll
  for (int j = 0; j < 16; ++j) {
    int rr = mt2 * 32 + (j & 3) + 8 * (j >> 2) + 4 * hi;
    float yv = z[j] + h_eff * yac[j];
    float er = h_eff * eac[j];
    float scl = 1e-3f + 1e-3f * fmaxf(fabsf(z[j]), fabsf(yv));
    float q = er / scl;
    p += q * q;
    yout[(size_t)(R0 + rr) * 64 + c2] = yv;
  }
  #pragma unroll
  for (int o = 32; o > 0; o >>= 1) p += __shfl_down(p, o, 64);
  if (l == 0) wpart[w] = p;
  __syncthreads();
  if (tid == 0) parts[blockIdx.x] = (wpart[0] + wpart[1]) + (wpart[2] + wpart[3]);
}

// ---------------- controller: err_norm -> accept/t/h/done/parity ----------------
__global__ void reduce_kernel(float* __restrict__ sc, const float* __restrict__ parts)
{
  if (((const int*)sc)[2]) return;
  __shared__ float s[256];
  int tid = threadIdx.x;
  float v = 0.f;
  for (int i = tid; i < 2048; i += 256) v += parts[i];
  s[tid] = v;
  __syncthreads();
  #pragma unroll
  for (int o = 128; o > 0; o >>= 1) {
    if (tid < o) s[tid] += s[tid + o];
    __syncthreads();
  }
  if (tid == 0) {
    float t = sc[0], h = sc[1];
    float h_eff = fminf(h, 1.0f - t);
    float en = fmaxf(sqrtf(s[0] * (1.0f / 8388608.0f)), 1e-8f);
    float factor = fminf(fmaxf(0.9f * powf(en, -0.2f), 0.2f), 10.0f);
    sc[1] = h_eff * factor;
    if (en <= 1.0f) {
      float tn = t + h_eff;
      sc[0] = tn;
      ((int*)sc)[4] ^= 1;                     // accepted: z := y (parity flip)
      if (tn >= 1.0f - 1e-7f) ((int*)sc)[2] = 1;
    }
  }
}

// ---------------- output head ----------------
__global__ __launch_bounds__(256, 1) void head_kernel(
  const float* __restrict__ ut,
  const u16* __restrict__ Wh1, const u16* __restrict__ Wh2,
  const float* __restrict__ bh1, const float* __restrict__ bh2,
  const float* __restrict__ sc,
  const float* __restrict__ buf0, float* __restrict__ outz, float* __restrict__ outy)
{
  __shared__ __align__(16) u16 X2[64 * 384];
  __shared__ float bh1s[128];
  __shared__ float bh2s[32];
  const int tid = threadIdx.x, w = tid >> 6, l = tid & 63, lo = l & 31, hi = l >> 5;
  const int R0 = blockIdx.x * 64;
  const int cur = ((const int*)sc)[4];
  const float* __restrict__ zf = cur ? outz : buf0;
  if (tid < 128) bh1s[tid] = bh1[tid];
  if (tid < 32)  bh2s[tid] = bh2[tid];
  for (int idx = tid; idx < 64 * 80; idx += 256) {
    int r = idx / 80, c = idx - r * 80;
    float v;
    if (c < 64) {
      v = zf[(size_t)(R0 + r) * 64 + c];
      if (cur == 0) outz[(size_t)(R0 + r) * 64 + c] = v;  // ensure zt1 lands in d_out
    } else {
      v = ut[(size_t)(R0 + r) * 16 + (c - 64)];
    }
    X2[x2i(r, c)] = f2b(v);
  }
  const int mt = w & 1, ntg = (w >> 1) * 2;
  bf16x8 w1f[2][5];
  #pragma unroll
  for (int nt = 0; nt < 2; ++nt)
    #pragma unroll
    for (int kc = 0; kc < 5; ++kc)
      w1f[nt][kc] = *(const bf16x8*)(Wh1 + (((ntg + nt) * 5 + kc) * 64 + l) * 8);
  bf16x8 w2f[8];
  #pragma unroll
  for (int kc = 0; kc < 8; ++kc)
    w2f[kc] = *(const bf16x8*)(Wh2 + (kc * 64 + l) * 8);
  __syncthreads();
  f32x16 a1[2];
  #pragma unroll
  for (int nt = 0; nt < 2; ++nt)
    #pragma unroll
    for (int j = 0; j < 16; ++j) a1[nt][j] = 0.f;
  const int ar = mt * 32 + lo;
  #pragma unroll
  for (int kc = 0; kc < 5; ++kc) {
    const bf16x8 af = *(const bf16x8*)&X2[ar * 384 + (((kc * 2 + hi) ^ (ar & 7)) << 3)];
    #pragma unroll
    for (int nt = 0; nt < 2; ++nt)
      a1[nt] = __builtin_amdgcn_mfma_f32_32x32x16_bf16(af, w1f[nt][kc], a1[nt], 0, 0, 0);
  }
  #pragma unroll
  for (int nt = 0; nt < 2; ++nt) {
    const int n = (ntg + nt) * 32 + lo;
    const float bb = bh1s[n];
    #pragma unroll
    for (int j = 0; j < 16; ++j) {
      float x = fmaxf(a1[nt][j] + bb, 0.f);
      int rr = mt * 32 + (j & 3) + 8 * (j >> 2) + 4 * hi;
      X2[x2i(rr, 80 + n)] = f2b(x);
    }
  }
  __syncthreads();
  if (w < 2) {
    f32x16 a2;
    #pragma unroll
    for (int j = 0; j < 16; ++j) a2[j] = 0.f;
    const int ar2 = w * 32 + lo;
    #pragma unroll
    for (int kc = 0; kc < 8; ++kc) {
      const int col0 = 80 + kc * 16 + hi * 8;
      const bf16x8 af = *(const bf16x8*)&X2[ar2 * 384 + (((col0 >> 3) ^ (ar2 & 7)) << 3)];
      a2 = __builtin_amdgcn_mfma_f32_32x32x16_bf16(af, w2f[kc], a2, 0, 0, 0);
    }
    if (lo < 20) {
      #pragma unroll
      for (int j = 0; j < 16; ++j) {
        int rr = w * 32 + (j & 3) + 8 * (j >> 2) + 4 * hi;
        outy[(size_t)(R0 + rr) * 20 + lo] = a2[j] + bh2s[lo];
      }
    }
  }
}

extern "C" void kernel_launch(void* const* d_in, const int* in_sizes, int n_in,
                              void* d_out, int out_size, void* d_ws, size_t ws_size,
                              hipStream_t stream) {
  const float* zt  = (const float*)d_in[0];
  // d_in[1] = dt (unused by the reference forward)
  const float* ut  = (const float*)d_in[2];
  const float* L   = (const float*)d_in[3];
  const float* aw1 = (const float*)d_in[4];
  const float* ab1 = (const float*)d_in[5];
  const float* aw2 = (const float*)d_in[6];
  const float* ab2 = (const float*)d_in[7];
  const float* rw1 = (const float*)d_in[8];
  const float* rb1 = (const float*)d_in[9];
  const float* rw2 = (const float*)d_in[10];
  const float* rb2 = (const float*)d_in[11];
  const float* ow1 = (const float*)d_in[12];
  const float* ob1 = (const float*)d_in[13];
  const float* ow2 = (const float*)d_in[14];
  const float* ob2 = (const float*)d_in[15];

  char* ws = (char*)d_ws;
  float* buf0  = (float*)ws;
  u16*   Wf1   = (u16*)(ws + OFF_WF1);
  u16*   Wf2   = (u16*)(ws + OFF_WF2);
  u16*   Wh1   = (u16*)(ws + OFF_WH1);
  u16*   Wh2   = (u16*)(ws + OFF_WH2);
  float* b1c   = (float*)(ws + OFF_B1);
  float* b2c   = (float*)(ws + OFF_B2);
  float* bh1   = (float*)(ws + OFF_BH1);
  float* bh2   = (float*)(ws + OFF_BH2);
  float* sc    = (float*)(ws + OFF_SC);
  float* parts = (float*)(ws + OFF_PARTS);
  float* outz  = (float*)d_out;                    // zt1 region doubles as ping-pong buf1
  float* outy  = outz + (size_t)131072 * 64;

  hipLaunchKernelGGL(setup_kernel, dim3(64), dim3(256), 0, stream,
      L, aw1, ab1, aw2, ab2, rw1, rb1, rw2, rb2, ow1, ob1, ow2, ob2,
      Wf1, Wf2, Wh1, Wh2, b1c, b2c, bh1, bh2);
  hipLaunchKernelGGL(init_kernel, dim3(2048), dim3(256), 0, stream, zt, buf0, sc, parts);
  for (int s = 0; s < 40; ++s) {
    hipLaunchKernelGGL(step_kernel, dim3(2048), dim3(256), 0, stream,
        ut, Wf1, Wf2, b1c, b2c, sc, parts, buf0, outz);
    hipLaunchKernelGGL(reduce_kernel, dim3(1), dim3(256), 0, stream, sc, parts);
  }
  hipLaunchKernelGGL(head_kernel, dim3(2048), dim3(256), 0, stream,
      ut, Wh1, Wh2, bh1, bh2, sc, buf0, outz, outy);
}

// Round 2
// 825.040 us; speedup vs baseline: 2.0009x; 2.0009x over previous
//
#include <hip/hip_runtime.h>

typedef unsigned short u16;
typedef unsigned int u32;
typedef __attribute__((ext_vector_type(8))) __bf16 bf16x8;
typedef __attribute__((ext_vector_type(16))) float f32x16;

#define NTB 768
#define TILES 4096
#define BROWS 32

#define F32(x) ((float)(x))
constexpr float DA10 = F32(1.0/5.0);
constexpr float DA20 = F32(3.0/40.0),      DA21 = F32(9.0/40.0);
constexpr float DA30 = F32(44.0/45.0),     DA31 = F32(-56.0/15.0),    DA32 = F32(32.0/9.0);
constexpr float DA40 = F32(19372.0/6561.0),DA41 = F32(-25360.0/2187.0),DA42 = F32(64448.0/6561.0), DA43 = F32(-212.0/729.0);
constexpr float DA50 = F32(9017.0/3168.0), DA51 = F32(-355.0/33.0),   DA52 = F32(46732.0/5247.0), DA53 = F32(49.0/176.0), DA54 = F32(-5103.0/18656.0);
constexpr float DB50 = F32(35.0/384.0), DB52 = F32(500.0/1113.0), DB53 = F32(125.0/192.0),
                DB54 = F32(-2187.0/6784.0), DB55 = F32(11.0/84.0);
constexpr float DE0 = F32(35.0/384.0 - 5179.0/57600.0);
constexpr float DE2 = F32(500.0/1113.0 - 7571.0/16695.0);
constexpr float DE3 = F32(125.0/192.0 - 393.0/640.0);
constexpr float DE4 = F32(-2187.0/6784.0 + 92097.0/339200.0);
constexpr float DE5 = F32(11.0/84.0 - 187.0/2100.0);
constexpr float DE6 = F32(-1.0/40.0);

// ws layout (bytes)
#define OFF_WF1   33554432
#define OFF_WF2   33603584
#define OFF_WH1   33646592
#define OFF_WH2   33671168
#define OFF_SC    33680384
#define OFF_PARTS 33680448

__device__ __forceinline__ u16 f2bf(float f) {
  __bf16 h = (__bf16)f;
  return __builtin_bit_cast(u16, h);
}
__device__ __forceinline__ u32 pk2(float a, float b) {
  return (u32)f2bf(a) | ((u32)f2bf(b) << 16);
}
__device__ __forceinline__ float bfl(u32 u) { return __builtin_bit_cast(float, u << 16); }
__device__ __forceinline__ float bfh(u32 u) { return __builtin_bit_cast(float, u & 0xffff0000u); }
__device__ __forceinline__ float tanhf_(float x) {
  float e = __expf(2.0f * x);
  return 1.0f - 2.0f / (e + 1.0f);
}
// X2 u16 index: row stride 384 elems (48 granules of 8), granule ^= row&7
__device__ __forceinline__ int xi(int r, int c) {
  return r * 384 + (((c >> 3) ^ (r & 7)) << 3) + (c & 7);
}

// ---------------- setup: pack weights as MFMA A-operand frags (m = output col) ----
// A-frag 32x32x16: lane l holds A[m = tile*32 + (l&31)][k = kc*16 + (l>>5)*8 + e]
__global__ void setup_kernel(const float* __restrict__ L,
  const float* __restrict__ aw1, const float* __restrict__ ab1,
  const float* __restrict__ aw2, const float* __restrict__ ab2,
  const float* __restrict__ rw1, const float* __restrict__ rb1,
  const float* __restrict__ rw2, const float* __restrict__ rb2,
  const float* __restrict__ ow1, const float* __restrict__ ob1,
  const float* __restrict__ ow2, const float* __restrict__ ob2,
  u16* __restrict__ Wf1, u16* __restrict__ Wf2,
  u16* __restrict__ Wh1, u16* __restrict__ Wh2)
{
  const int gid = blockIdx.x * blockDim.x + threadIdx.x;
  const int gstr = gridDim.x * blockDim.x;
  for (int i = gid; i < 62976; i += gstr) {
    float v; u16* dst;
    if (i < 24576) {               // Wf1: [wt 0..7][kc 0..5]  K = z(64)|u(16)|ones(16)
      const int j = i, e = j & 7, l = (j >> 3) & 63, f = j >> 9;
      const int wt = f / 6, kc = f - wt * 6;
      const int n = wt * 32 + (l & 31);
      const int k = kc * 16 + (l >> 5) * 8 + e;
      if (k < 80)       v = (n < 128) ? aw1[n * 80 + k] : rw1[(n - 128) * 80 + k];
      else if (k == 80) v = (n < 128) ? ab1[n] : rb1[n - 128];
      else              v = 0.0f;
      dst = Wf1 + j;
    } else if (i < 46080) {        // Wf2: [lt 0..1][kc 0..20] K = z(64)|bias(16)|H(256)
      const int j = i - 24576, e = j & 7, l = (j >> 3) & 63, f = j >> 9;
      const int lt = f / 21, kc = f - lt * 21;
      const int m = lt * 32 + (l & 31);
      const int kk = kc * 16 + (l >> 5) * 8 + e;
      if (kk < 64) {               // A = -(L L^T): dz_diff[r][m] = sum_q z[r][q] * A[m][q]
        float s = 0.0f;
        for (int q2 = 0; q2 < 64; ++q2) s += L[m * 64 + q2] * L[kk * 64 + q2];
        v = -s;
      } else if (kk == 64) v = ab2[m] + rb2[m];
      else if (kk < 80)    v = 0.0f;
      else if (kk < 208)   v = aw2[m * 128 + (kk - 80)];
      else                 v = rw2[m * 128 + (kk - 208)];
      dst = Wf2 + j;
    } else if (i < 58368) {        // Wh1: [wt 0..3][kc 0..5]
      const int j = i - 46080, e = j & 7, l = (j >> 3) & 63, f = j >> 9;
      const int wt = f / 6, kc = f - wt * 6;
      const int n = wt * 32 + (l & 31);
      const int k = kc * 16 + (l >> 5) * 8 + e;
      if (k < 80)       v = ow1[n * 80 + k];
      else if (k == 80) v = ob1[n];
      else              v = 0.0f;
      dst = Wh1 + j;
    } else {                       // Wh2: [kc 0..8]  K = bias(16)|H(128), out pad 20->32
      const int j = i - 58368, e = j & 7, l = (j >> 3) & 63, kc = j >> 9;
      const int m = l & 31;
      const int koff = (l >> 5) * 8 + e;
      if (m >= 20)      v = 0.0f;
      else if (kc == 0) v = (koff == 0) ? ob2[m] : 0.0f;
      else              v = ow2[m * 128 + ((kc - 1) * 16 + koff)];
      dst = Wh2 + j;
    }
    *dst = f2bf(v);
  }
}

// ---------------- init ----------------
__global__ void init_kernel(const float* __restrict__ zt, float* __restrict__ buf0,
                            float* __restrict__ sc, float* __restrict__ parts)
{
  const int gid = blockIdx.x * 256 + threadIdx.x;
  const float4* s = (const float4*)zt;
  float4* d = (float4*)buf0;
  #pragma unroll
  for (int p = 0; p < 8; ++p) { const int i = p * 262144 + gid; d[i] = s[i]; }
  if (blockIdx.x == 0) {
    for (int i = threadIdx.x; i < NTB; i += 256) parts[i] = 0.0f;
    if (threadIdx.x == 0) {
      sc[0] = 0.0f;             // t
      sc[1] = 0.1f;             // h
      ((int*)sc)[2] = 0;        // done
      ((u32*)sc)[3] = 0u;       // arrival counter
      ((int*)sc)[4] = 0;        // parity
    }
  }
}

// ---------------- dopri5 step (fused controller) ----------------
// 32-row tiles; 4 waves: lt = w&1 (latent col tile), kh = w>>1 (GEMM2 K-half)
__global__ __launch_bounds__(256, 2) void step_kernel(
    const float* __restrict__ ut,
    const u16* __restrict__ Wf1, const u16* __restrict__ Wf2,
    float* __restrict__ sc, float* __restrict__ parts,
    float* __restrict__ buf0, float* __restrict__ buf1)
{
  if (((const int*)sc)[2]) return;   // done
  __shared__ __align__(16) u16 X2[BROWS * 384];        // [z|u|ones|H] bf16, swizzled
  __shared__ __align__(16) u16 KS[4 * BROWS * 68];     // k1..k4 bf16, row stride 68
  __shared__ __align__(16) float RED[2][4][64][4];     // GEMM2 K-half exchange
  __shared__ int lastFlag;
  const int tid = threadIdx.x, w = tid >> 6, l = tid & 63, lo = l & 31, hi = l >> 5;
  const int lt = w & 1, kh = w >> 1;
  const float t = sc[0], h = sc[1];
  const int cur = ((const int*)sc)[4];
  const float he = fminf(h, 1.0f - t);
  const float* __restrict__ zin = cur ? buf1 : buf0;
  float* __restrict__ yout = cur ? buf0 : buf1;

  // weight frags (deduped): GEMM1 wt = {2w, 2w+1}; GEMM2 lt x K-half
  bf16x8 wa[6], wb[6];
  #pragma unroll
  for (int kc = 0; kc < 6; ++kc) {
    wa[kc] = *(const bf16x8*)(Wf1 + (((2 * w)     * 6 + kc) * 64 + l) * 8);
    wb[kc] = *(const bf16x8*)(Wf1 + (((2 * w + 1) * 6 + kc) * 64 + l) * 8);
  }
  bf16x8 w2[11];
  #pragma unroll
  for (int i = 0; i < 11; ++i) {
    const int kc = kh ? (i < 10 ? 11 + i : 20) : i;
    w2[i] = *(const bf16x8*)(Wf2 + ((lt * 21 + kc) * 64 + l) * 8);
  }

  float perr = 0.0f;

  for (int tile = blockIdx.x; tile < TILES; tile += NTB) {
    const int R0 = tile * BROWS;
    // stage u + ones (cols 64..95): 1024 elems, 4/thread
    {
      const int r = tid >> 3, c0 = 64 + (tid & 7) * 4;
      float v0, v1, v2, v3;
      if (c0 < 80) {
        const float4 uv = *(const float4*)&ut[(size_t)(R0 + r) * 16 + (c0 - 64)];
        v0 = uv.x; v1 = uv.y; v2 = uv.z; v3 = uv.w;
      } else { v0 = (c0 == 80) ? 1.0f : 0.0f; v1 = v2 = v3 = 0.0f; }
      *(uint2*)&X2[xi(r, c0)] = make_uint2(pk2(v0, v1), pk2(v2, v3));
    }
    // z state: kh==0 waves own (row = lo, cols lt*32 + q*8 + 4hi + i)
    f32x16 z, yac, eac, kp;
    if (kh == 0) {
      #pragma unroll
      for (int q = 0; q < 4; ++q) {
        const float4 zq = *(const float4*)&zin[(size_t)(R0 + lo) * 64 + lt * 32 + q * 8 + 4 * hi];
        z[4*q] = zq.x; z[4*q+1] = zq.y; z[4*q+2] = zq.z; z[4*q+3] = zq.w;
        *(uint2*)&X2[xi(lo, lt * 32 + q * 8 + 4 * hi)] =
            make_uint2(pk2(zq.x, zq.y), pk2(zq.z, zq.w));
      }
    }

    auto feval = [&]() -> f32x16 {
      __syncthreads();                           // zi visible / RED consumed
      // GEMM1: H^T[m=wcol][n=row] = W1 x zu^T ; K = 96
      f32x16 a0{}, a1{};
      #pragma unroll
      for (int kc = 0; kc < 6; ++kc) {
        const bf16x8 bf = *(const bf16x8*)&X2[xi(lo, kc * 16 + hi * 8)];
        a0 = __builtin_amdgcn_mfma_f32_32x32x16_bf16(wa[kc], bf, a0, 0, 0, 0);
        a1 = __builtin_amdgcn_mfma_f32_32x32x16_bf16(wb[kc], bf, a1, 0, 0, 0);
      }
      {
        const int hc0 = 96 + (2 * w) * 32 + 4 * hi;
        #pragma unroll
        for (int q = 0; q < 4; ++q) {
          const float e0 = tanhf_(a0[4*q]),   e1 = tanhf_(a0[4*q+1]);
          const float e2 = tanhf_(a0[4*q+2]), e3 = tanhf_(a0[4*q+3]);
          *(uint2*)&X2[xi(lo, hc0 + q * 8)] = make_uint2(pk2(e0, e1), pk2(e2, e3));
        }
        const int hc1 = 96 + (2 * w + 1) * 32 + 4 * hi;
        #pragma unroll
        for (int q = 0; q < 4; ++q) {
          const float e0 = tanhf_(a1[4*q]),   e1 = tanhf_(a1[4*q+1]);
          const float e2 = tanhf_(a1[4*q+2]), e3 = tanhf_(a1[4*q+3]);
          *(uint2*)&X2[xi(lo, hc1 + q * 8)] = make_uint2(pk2(e0, e1), pk2(e2, e3));
        }
      }
      __syncthreads();                           // H visible
      // GEMM2: dz^T[m=latent][n=row]; K = 336 split 11/10 over kh
      f32x16 p{};
      #pragma unroll
      for (int i = 0; i < 10; ++i) {
        const int kc = kh ? (11 + i) : i;
        const int kcol = (kc < 4) ? kc * 16 : 80 + (kc - 4) * 16;
        const bf16x8 bf = *(const bf16x8*)&X2[xi(lo, kcol + hi * 8)];
        p = __builtin_amdgcn_mfma_f32_32x32x16_bf16(w2[i], bf, p, 0, 0, 0);
      }
      if (kh == 0) {
        const bf16x8 bf = *(const bf16x8*)&X2[xi(lo, 176 + hi * 8)];   // kc=10
        p = __builtin_amdgcn_mfma_f32_32x32x16_bf16(w2[10], bf, p, 0, 0, 0);
      } else {
        #pragma unroll
        for (int q = 0; q < 4; ++q)
          *(float4*)&RED[lt][q][l][0] = make_float4(p[4*q], p[4*q+1], p[4*q+2], p[4*q+3]);
      }
      __syncthreads();                           // RED visible
      if (kh == 0) {
        #pragma unroll
        for (int q = 0; q < 4; ++q) {
          const float4 r4 = *(const float4*)&RED[lt][q][l][0];
          p[4*q] += r4.x; p[4*q+1] += r4.y; p[4*q+2] += r4.z; p[4*q+3] += r4.w;
        }
      }
      return p;
    };

    auto stks = [&](int slot, const f32x16& k) {
      #pragma unroll
      for (int q = 0; q < 4; ++q)
        *(uint2*)&KS[(slot * BROWS + lo) * 68 + lt * 32 + q * 8 + 4 * hi] =
            make_uint2(pk2(k[4*q], k[4*q+1]), pk2(k[4*q+2], k[4*q+3]));
    };
    auto addks = [&](int slot, float c, f32x16& zi) {
      #pragma unroll
      for (int q = 0; q < 4; ++q) {
        const uint2 v = *(const uint2*)&KS[(slot * BROWS + lo) * 68 + lt * 32 + q * 8 + 4 * hi];
        zi[4*q]   += c * bfl(v.x); zi[4*q+1] += c * bfh(v.x);
        zi[4*q+2] += c * bfl(v.y); zi[4*q+3] += c * bfh(v.y);
      }
    };
    auto stzi = [&](const f32x16& zi) {
      #pragma unroll
      for (int q = 0; q < 4; ++q)
        *(uint2*)&X2[xi(lo, lt * 32 + q * 8 + 4 * hi)] =
            make_uint2(pk2(zi[4*q], zi[4*q+1]), pk2(zi[4*q+2], zi[4*q+3]));
    };

    kp = feval();                                 // k1
    if (kh == 0) {
      f32x16 zi;
      #pragma unroll
      for (int j = 0; j < 16; ++j) {
        yac[j] = DB50 * kp[j]; eac[j] = DE0 * kp[j];
        zi[j] = z[j] + he * (DA10 * kp[j]);
      }
      stks(0, kp); stzi(zi);
    }
    kp = feval();                                 // k2
    if (kh == 0) {
      f32x16 zi;
      #pragma unroll
      for (int j = 0; j < 16; ++j) zi[j] = z[j] + he * (DA21 * kp[j]);
      addks(0, he * DA20, zi);
      stks(1, kp); stzi(zi);
    }
    kp = feval();                                 // k3
    if (kh == 0) {
      f32x16 zi;
      #pragma unroll
      for (int j = 0; j < 16; ++j) {
        yac[j] += DB52 * kp[j]; eac[j] += DE2 * kp[j];
        zi[j] = z[j] + he * (DA32 * kp[j]);
      }
      addks(0, he * DA30, zi); addks(1, he * DA31, zi);
      stks(2, kp); stzi(zi);
    }
    kp = feval();                                 // k4
    if (kh == 0) {
      f32x16 zi;
      #pragma unroll
      for (int j = 0; j < 16; ++j) {
        yac[j] += DB53 * kp[j]; eac[j] += DE3 * kp[j];
        zi[j] = z[j] + he * (DA43 * kp[j]);
      }
      addks(0, he * DA40, zi); addks(1, he * DA41, zi); addks(2, he * DA42, zi);
      stks(3, kp); stzi(zi);
    }
    kp = feval();                                 // k5
    if (kh == 0) {
      f32x16 zi;
      #pragma unroll
      for (int j = 0; j < 16; ++j) {
        yac[j] += DB54 * kp[j]; eac[j] += DE4 * kp[j];
        zi[j] = z[j] + he * (DA54 * kp[j]);
      }
      addks(0, he * DA50, zi); addks(1, he * DA51, zi);
      addks(2, he * DA52, zi); addks(3, he * DA53, zi);
      stzi(zi);
    }
    kp = feval();                                 // k6
    if (kh == 0) {
      f32x16 zi;
      #pragma unroll
      for (int j = 0; j < 16; ++j) {
        yac[j] += DB55 * kp[j]; eac[j] += DE5 * kp[j];
        zi[j] = z[j] + he * yac[j];
      }
      stzi(zi);
    }
    kp = feval();                                 // k7
    if (kh == 0) {
      #pragma unroll
      for (int q = 0; q < 4; ++q) {
        float4 y4;
        float* yp = (float*)&y4;
        #pragma unroll
        for (int i2 = 0; i2 < 4; ++i2) {
          const int j = 4 * q + i2;
          eac[j] += DE6 * kp[j];
          const float yv = z[j] + he * yac[j];
          const float er = he * eac[j];
          const float scl = 1e-3f + 1e-3f * fmaxf(fabsf(z[j]), fabsf(yv));
          const float qq = er / scl;
          perr += qq * qq;
          yp[i2] = yv;
        }
        *(float4*)&yout[(size_t)(R0 + lo) * 64 + lt * 32 + q * 8 + 4 * hi] = y4;
      }
    }
  } // tile loop

  __syncthreads();                                // protect RED reuse
  float pr = perr;
  #pragma unroll
  for (int o = 32; o > 0; o >>= 1) pr += __shfl_down(pr, o, 64);
  float* rs = &RED[0][0][0][0];
  if (l == 0) rs[w] = pr;
  __syncthreads();
  if (tid == 0) {
    parts[blockIdx.x] = (rs[0] + rs[1]) + (rs[2] + rs[3]);
    __threadfence();
    lastFlag = (atomicAdd((u32*)sc + 3, 1u) == (u32)(NTB - 1)) ? 1 : 0;
  }
  __syncthreads();
  if (lastFlag) {                                 // controller in last block
    __threadfence();
    float v = 0.0f;
    for (int i = tid; i < NTB; i += 256) v += parts[i];
    rs[tid] = v;
    __syncthreads();
    #pragma unroll
    for (int o = 128; o > 0; o >>= 1) {
      if (tid < o) rs[tid] += rs[tid + o];
      __syncthreads();
    }
    if (tid == 0) {
      ((u32*)sc)[3] = 0u;
      const float en = fmaxf(sqrtf(rs[0] * (1.0f / 8388608.0f)), 1e-8f);
      const float factor = fminf(fmaxf(0.9f * __powf(en, -0.2f), 0.2f), 10.0f);
      sc[1] = he * factor;
      if (en <= 1.0f) {
        const float tn = t + he;
        sc[0] = tn;
        ((int*)sc)[4] = cur ^ 1;
        if (tn >= 1.0f - 1e-7f) ((int*)sc)[2] = 1;
      }
    }
  }
}

// ---------------- output head ----------------
__global__ __launch_bounds__(256, 2) void head_kernel(
    const float* __restrict__ ut,
    const u16* __restrict__ Wh1, const u16* __restrict__ Wh2,
    const float* __restrict__ sc,
    const float* __restrict__ buf0, float* __restrict__ outz, float* __restrict__ outy)
{
  __shared__ __align__(16) u16 X2[BROWS * 384];
  const int tid = threadIdx.x, w = tid >> 6, l = tid & 63, lo = l & 31, hi = l >> 5;
  const int cur = ((const int*)sc)[4];
  const float* __restrict__ zf = cur ? outz : buf0;

  bf16x8 w1f[6];
  #pragma unroll
  for (int kc = 0; kc < 6; ++kc)
    w1f[kc] = *(const bf16x8*)(Wh1 + ((w * 6 + kc) * 64 + l) * 8);
  bf16x8 w2f[9];
  #pragma unroll
  for (int kc = 0; kc < 9; ++kc)
    w2f[kc] = *(const bf16x8*)(Wh2 + (kc * 64 + l) * 8);

  for (int tile = blockIdx.x; tile < TILES; tile += NTB) {
    const int R0 = tile * BROWS;
    {
      const int r = tid >> 3, c0 = (tid & 7) * 8;
      const float4 a = *(const float4*)&zf[(size_t)(R0 + r) * 64 + c0];
      const float4 b = *(const float4*)&zf[(size_t)(R0 + r) * 64 + c0 + 4];
      if (cur == 0) {     // final z lives in buf0: copy into d_out zt1 region
        *(float4*)&outz[(size_t)(R0 + r) * 64 + c0] = a;
        *(float4*)&outz[(size_t)(R0 + r) * 64 + c0 + 4] = b;
      }
      *(uint2*)&X2[xi(r, c0)]     = make_uint2(pk2(a.x, a.y), pk2(a.z, a.w));
      *(uint2*)&X2[xi(r, c0 + 4)] = make_uint2(pk2(b.x, b.y), pk2(b.z, b.w));
      const int c1 = 64 + (tid & 7) * 4;
      float v0, v1, v2, v3;
      if (c1 < 80) {
        const float4 uv = *(const float4*)&ut[(size_t)(R0 + r) * 16 + (c1 - 64)];
        v0 = uv.x; v1 = uv.y; v2 = uv.z; v3 = uv.w;
      } else { v0 = (c1 == 80) ? 1.0f : 0.0f; v1 = v2 = v3 = 0.0f; }
      *(uint2*)&X2[xi(r, c1)] = make_uint2(pk2(v0, v1), pk2(v2, v3));
    }
    __syncthreads();
    // GEMM1: wave w -> H cols 96+32w, relu
    f32x16 a{};
    #pragma unroll
    for (int kc = 0; kc < 6; ++kc) {
      const bf16x8 bf = *(const bf16x8*)&X2[xi(lo, kc * 16 + hi * 8)];
      a = __builtin_amdgcn_mfma_f32_32x32x16_bf16(w1f[kc], bf, a, 0, 0, 0);
    }
    {
      const int hc = 96 + w * 32 + 4 * hi;
      #pragma unroll
      for (int q = 0; q < 4; ++q) {
        const float e0 = fmaxf(a[4*q],   0.0f), e1 = fmaxf(a[4*q+1], 0.0f);
        const float e2 = fmaxf(a[4*q+2], 0.0f), e3 = fmaxf(a[4*q+3], 0.0f);
        *(uint2*)&X2[xi(lo, hc + q * 8)] = make_uint2(pk2(e0, e1), pk2(e2, e3));
      }
    }
    __syncthreads();
    if (w == 0) {
      f32x16 p{};
      #pragma unroll
      for (int kc = 0; kc < 9; ++kc) {
        const bf16x8 bf = *(const bf16x8*)&X2[xi(lo, 80 + kc * 16 + hi * 8)];
        p = __builtin_amdgcn_mfma_f32_32x32x16_bf16(w2f[kc], bf, p, 0, 0, 0);
      }
      #pragma unroll
      for (int q = 0; q < 3; ++q) {
        const int c = q * 8 + 4 * hi;
        if (c < 20) {
          *(float4*)&outy[(size_t)(R0 + lo) * 20 + c] =
              make_float4(p[4*q], p[4*q+1], p[4*q+2], p[4*q+3]);
        }
      }
    }
    __syncthreads();   // wave0 GEMM2 reads done before next tile staging
  }
}

extern "C" void kernel_launch(void* const* d_in, const int* in_sizes, int n_in,
                              void* d_out, int out_size, void* d_ws, size_t ws_size,
                              hipStream_t stream) {
  const float* zt  = (const float*)d_in[0];
  const float* ut  = (const float*)d_in[2];
  const float* L   = (const float*)d_in[3];
  const float* aw1 = (const float*)d_in[4];
  const float* ab1 = (const float*)d_in[5];
  const float* aw2 = (const float*)d_in[6];
  const float* ab2 = (const float*)d_in[7];
  const float* rw1 = (const float*)d_in[8];
  const float* rb1 = (const float*)d_in[9];
  const float* rw2 = (const float*)d_in[10];
  const float* rb2 = (const float*)d_in[11];
  const float* ow1 = (const float*)d_in[12];
  const float* ob1 = (const float*)d_in[13];
  const float* ow2 = (const float*)d_in[14];
  const float* ob2 = (const float*)d_in[15];

  char* ws = (char*)d_ws;
  float* buf0  = (float*)ws;
  u16*   Wf1   = (u16*)(ws + OFF_WF1);
  u16*   Wf2   = (u16*)(ws + OFF_WF2);
  u16*   Wh1   = (u16*)(ws + OFF_WH1);
  u16*   Wh2   = (u16*)(ws + OFF_WH2);
  float* sc    = (float*)(ws + OFF_SC);
  float* parts = (float*)(ws + OFF_PARTS);
  float* outz  = (float*)d_out;                    // zt1 region doubles as ping-pong buf1
  float* outy  = outz + (size_t)131072 * 64;

  hipLaunchKernelGGL(setup_kernel, dim3(64), dim3(256), 0, stream,
      L, aw1, ab1, aw2, ab2, rw1, rb1, rw2, rb2, ow1, ob1, ow2, ob2,
      Wf1, Wf2, Wh1, Wh2);
  hipLaunchKernelGGL(init_kernel, dim3(1024), dim3(256), 0, stream, zt, buf0, sc, parts);
  for (int s = 0; s < 40; ++s) {
    hipLaunchKernelGGL(step_kernel, dim3(NTB), dim3(256), 0, stream,
        ut, Wf1, Wf2, sc, parts, buf0, outz);
  }
  hipLaunchKernelGGL(head_kernel, dim3(NTB), dim3(256), 0, stream,
      ut, Wh1, Wh2, sc, buf0, outz, outy);
}